// Round 6
// baseline (1088.109 us; speedup 1.0000x reference)
//
#include <hip/hip_runtime.h>

#define NN      100000      // nodes
#define NN2     100352      // nodes padded to 512 (196 tiles of 512)
#define NE      400000      // raw edges
#define ETOT    500000      // edges + self loops
#define NG      4000        // graphs
#define W3D     384
#define HIDD    128
#define NCLS    10
#define NSLICE  256         // stat accumulation slices

typedef unsigned short u16;
typedef unsigned int   u32;
typedef unsigned long long u64;
typedef __attribute__((ext_vector_type(8))) short short8;
typedef __attribute__((ext_vector_type(4))) float f32x4;

static __device__ __forceinline__ float bf2f(u16 u) {
  return __uint_as_float(((u32)u) << 16);
}
static __device__ __forceinline__ float bflo(u32 u) {
  return __uint_as_float(u << 16);
}
static __device__ __forceinline__ float bfhi(u32 u) {
  return __uint_as_float(u & 0xffff0000u);
}
static __device__ __forceinline__ u16 f2b(float f) {
  u32 u = __float_as_uint(f);
  u32 r = (u + 0x7fffu + ((u >> 16) & 1u)) >> 16;
  return (u16)r;
}

// async global->LDS, 16 B per lane; LDS dest = wave-uniform base + lane*16
static __device__ __forceinline__ void llds16(const u16* g, u16* l) {
  __builtin_amdgcn_global_load_lds(
      (const __attribute__((address_space(1))) void*)(u64)(const void*)g,
      (__attribute__((address_space(3))) void*)(u64)(void*)l, 16, 0, 0);
}

#define WAITV0() asm volatile("s_waitcnt vmcnt(0)" ::: "memory")

// ---------------------------------------------------------------- fallback
__global__ void mg_zero_out(float* out, int n) {
  int i = blockIdx.x * 256 + threadIdx.x;
  if (i < n) out[i] = 0.f;
}

// ---------------------------------------------------------------- x -> bf16 [NN2][64] zero-padded
__global__ void mg_cvt_x(const float* __restrict__ x, u16* __restrict__ Xb) {
  int idx = blockIdx.x * 256 + threadIdx.x;
  if (idx >= NN2 * 64) return;
  int row = idx >> 6, col = idx & 63;
  Xb[idx] = (row < NN && col < 32) ? f2b(x[row * 32 + col]) : (u16)0;
}

// ---------------------------------------------------------------- transpose
// out[n][kp] = bf16(in[kp][n]) for kp<K, zero-padded to Kpad (= K+8 pad for
// bank-conflict-reduced LDS rows; no swizzle).
__global__ void mg_transpose_pad(const float* __restrict__ in, u16* __restrict__ out,
                                 int K, int Nn, int Kpad) {
  int idx = blockIdx.x * 256 + threadIdx.x;
  if (idx >= Nn * Kpad) return;
  int n = idx / Kpad, kp = idx - n * Kpad;
  out[idx] = (kp < K) ? f2b(in[kp * Nn + n]) : (u16)0;
}

// ---------------------------------------------------------------- BN -> weight fold
// Wt [384][392] (8-col zero pad); output keeps the pad. Pads have w=0 so the
// clamped scale/shift index is harmless.
__global__ void mg_fold_w(const u16* __restrict__ Wt, const float* __restrict__ scale,
                          const float* __restrict__ shift, u16* __restrict__ Wp,
                          float* __restrict__ bp) {
  __shared__ float red[128];
  int j = blockIdx.x, t = threadIdx.x;   // 384 blocks x 128 threads
  const u16* src = Wt + (size_t)j * (W3D + 8);
  u16* dst = Wp + (size_t)j * (W3D + 8);
  float acc = 0.f;
  for (int kp = t; kp < W3D + 8; kp += 128) {
    int kt = (kp < W3D) ? kp : 0;
    float w = bf2f(src[kp]);             // pad entries are 0
    dst[kp] = f2b(w * scale[kt]);
    acc += w * shift[kt];
  }
  red[t] = acc; __syncthreads();
  for (int off = 64; off; off >>= 1) {
    if (t < off) red[t] += red[t + off];
    __syncthreads();
  }
  if (t == 0) bp[j] = red[0];
}

// ---------------------------------------------------------------- CSR build
__global__ void mg_edge_histo(const int* __restrict__ ei, int* __restrict__ deg) {
  int e = blockIdx.x * 256 + threadIdx.x;
  if (e >= ETOT) return;
  int d = (e < NE) ? ei[NE + e] : (e - NE);
  atomicAdd(&deg[d], 1);
}

__global__ void mg_scan1(const int* __restrict__ in, int* __restrict__ bsum, int n) {
  __shared__ int sd[256];
  int tid = threadIdx.x;
  int base = blockIdx.x * 1024 + tid * 4;
  int s = 0;
#pragma unroll
  for (int j = 0; j < 4; ++j) { int i = base + j; if (i < n) s += in[i]; }
  sd[tid] = s; __syncthreads();
  for (int off = 128; off > 0; off >>= 1) {
    if (tid < off) sd[tid] += sd[tid + off];
    __syncthreads();
  }
  if (tid == 0) bsum[blockIdx.x] = sd[0];
}

__global__ void mg_scan2(int* __restrict__ bsum, int nb) {
  __shared__ int sd[256];
  int tid = threadIdx.x;
  int v = (tid < nb) ? bsum[tid] : 0;
  sd[tid] = v; __syncthreads();
  for (int off = 1; off < 256; off <<= 1) {
    int t = (tid >= off) ? sd[tid - off] : 0;
    __syncthreads();
    sd[tid] += t;
    __syncthreads();
  }
  if (tid < nb) bsum[tid] = sd[tid] - v;   // exclusive
}

__global__ void mg_scan3(const int* __restrict__ in, const int* __restrict__ bexcl,
                         int* __restrict__ out, int n) {
  __shared__ int sd[256];
  int tid = threadIdx.x;
  int base = blockIdx.x * 1024 + tid * 4;
  int loc[4]; int s = 0;
#pragma unroll
  for (int j = 0; j < 4; ++j) { int i = base + j; loc[j] = (i < n) ? in[i] : 0; s += loc[j]; }
  sd[tid] = s; __syncthreads();
  for (int off = 1; off < 256; off <<= 1) {
    int t = (tid >= off) ? sd[tid - off] : 0;
    __syncthreads();
    sd[tid] += t;
    __syncthreads();
  }
  int run = sd[tid] - s + bexcl[blockIdx.x];
#pragma unroll
  for (int j = 0; j < 4; ++j) {
    int i = base + j;
    if (i < n) { out[i] = run; run += loc[j]; if (i == n - 1) out[n] = run; }
  }
}

__global__ void mg_edge_scatter(const int* __restrict__ ei, int* __restrict__ fill,
                                int* __restrict__ colsrc, int* __restrict__ dstc) {
  int e = blockIdx.x * 256 + threadIdx.x;
  if (e >= ETOT) return;
  int s, d;
  if (e < NE) { s = ei[e]; d = ei[NE + e]; } else { s = e - NE; d = s; }
  int pos = atomicAdd(&fill[d], 1);
  colsrc[pos] = s;
  dstc[pos] = d;
}

__global__ void mg_graph_ptr(const int* __restrict__ batch, int* __restrict__ gptr) {
  int g = blockIdx.x * 256 + threadIdx.x;
  if (g > NG) return;
  if (g == NG) { gptr[NG] = NN; return; }
  int lo = 0, hi = NN;
  while (lo < hi) { int mid = (lo + hi) >> 1; if (batch[mid] < g) lo = mid + 1; else hi = mid; }
  gptr[g] = lo;
}

// ---------------------------------------------------------------- edge softmax numerators
// p[e][h] = exp(leaky(es[src]+ed[dst]) - m_dst),  m_dst = leaky(es[dst]+ed[dst])
// 1 lane/edge, CSR order. es/ed are 1.6 MB each -> L2-resident gathers.
__global__ __launch_bounds__(256) void mg_edge_p(
    const int* __restrict__ colsrc, const int* __restrict__ dstc,
    const float* __restrict__ es, const float* __restrict__ ed,
    float* __restrict__ pcsr) {
  int e = blockIdx.x * 256 + threadIdx.x;
  if (e >= ETOT) return;
  int s = colsrc[e], d = dstc[e];
  float4 a = *(const float4*)(es + 4 * s);
  float4 sd = *(const float4*)(es + 4 * d);
  float4 dd = *(const float4*)(ed + 4 * d);
  float4 p;
  {
    float ev = a.x + dd.x; ev = (ev > 0.f) ? ev : 0.2f * ev;
    float mv = sd.x + dd.x; mv = (mv > 0.f) ? mv : 0.2f * mv;
    p.x = __expf(ev - mv);
  }
  {
    float ev = a.y + dd.y; ev = (ev > 0.f) ? ev : 0.2f * ev;
    float mv = sd.y + dd.y; mv = (mv > 0.f) ? mv : 0.2f * mv;
    p.y = __expf(ev - mv);
  }
  {
    float ev = a.z + dd.z; ev = (ev > 0.f) ? ev : 0.2f * ev;
    float mv = sd.z + dd.z; mv = (mv > 0.f) ? mv : 0.2f * mv;
    p.z = __expf(ev - mv);
  }
  p.w = 0.f;
  *(float4*)(pcsr + (size_t)e * 4) = p;
}

// ---------------------------------------------------------------- GEMM (bf16 MFMA)
// Round-15: 64 output rows per wave (acc[4][8]) -> per K-step a wave's
// 8 ds_read_b128 feed 32 MFMA (was 16). Diagnosis: three schedule rewrites
// all stuck at ~86-104us with MfmaUtil ~12% -> the stall is the per-wave
// LDS->MFMA dependency ratio at 2 waves/SIMD, not schedule depth. A-load
// chunking reverted to round-4's measured-best in-flight depth (8/wave).
// m-tile = 512 rows; NN2 padded to 100352 (196 tiles).
#define CP 136   // C-strip LDS row stride (u16), 16B-aligned rows

template<int K>
__global__ __launch_bounds__(512, 2) void mg_gemm(
    const u16* __restrict__ Ag, const u16* __restrict__ Bt,
    int MT, int Mstore, int Nn,
    u16* __restrict__ Cb, const float* __restrict__ bias, int relu,
    const float* __restrict__ asrc, const float* __restrict__ adst,
    float* __restrict__ aes, float* __restrict__ aed) {
  constexpr int KP = K + 8;
  constexpr int NITER = K / 32;
  constexpr int CSZ = (K == 64) ? 1 : 2;
  constexpr int CH = NITER / CSZ;        // 2,2,4,6 -> always even
  static_assert(CH * CSZ == NITER && (CH & 1) == 0, "chunking");
  __shared__ u16 lds[128 * KP + 8 * 16 * CP];
  u16* Blds = lds;
  int tid = threadIdx.x;
  int lane = tid & 63, wv = tid >> 6;

  // bijective XCD swizzle: work chunks per XCD contiguous, n-tile fastest
  int gx = gridDim.x, gy = gridDim.y;
  int nwg = gx * gy;
  int lin = (int)blockIdx.y * gx + blockIdx.x;
  int q = nwg >> 3, r8 = nwg & 7;
  int xcd = lin & 7, sidx = lin >> 3;
  int nlin = (xcd < r8) ? (xcd * (q + 1) + sidx)
                        : (r8 * (q + 1) + (xcd - r8) * q + sidx);
  int mchunk = nlin / gy;
  int nidx = nlin - mchunk * gy;
  int n0 = nidx * 128;

  int lr = lane & 15, lq = lane >> 4;

  // ---- stage the full B n-tile: 128*KP*2 bytes, linear copy
  {
    const u16* Bg = Bt + (size_t)n0 * KP;
    constexpr int BBYTES = 128 * KP * 2;
    constexpr int FULL = BBYTES / 8192;            // full 512-thread rounds
    constexpr int REMC = (BBYTES - FULL * 8192) / 16;  // leftover 16B chunks
#pragma unroll
    for (int s = 0; s < FULL; ++s) {
      int off = s * 4096 + wv * 512 + lane * 8;    // u16 units
      llds16(Bg + off, Blds + off);
    }
    if (REMC > 0 && wv * 64 + lane < REMC) {
      int off = FULL * 4096 + wv * 512 + lane * 8;
      llds16(Bg + off, Blds + off);
    }
  }

  // per-lane GEMM bias (col = n0 + ni*16 + lr)
  float bvv[8];
#pragma unroll
  for (int ni = 0; ni < 8; ++ni)
    bvv[ni] = bias ? bias[n0 + ni * 16 + lr] : 0.f;

  WAITV0();
  __syncthreads();   // the ONLY barrier: B tile visible to all waves

  u16* strip = lds + 128 * KP + wv * (16 * CP);

  int t0 = (int)(((long long)mchunk * MT) / gx);
  int t1 = (int)(((long long)(mchunk + 1) * MT) / gx);

  f32x4 acc[4][8];
  short8 bufE[4][CSZ], bufO[4][CSZ];

  auto loadCh = [&](short8 (&buf)[4][CSZ], int t, int ch) {
    const u16* Ar = Ag + (size_t)(t * 512 + wv * 64 + lr) * K + lq * 8 + ch * (CSZ * 32);
#pragma unroll
    for (int mi = 0; mi < 4; ++mi)
#pragma unroll
      for (int s = 0; s < CSZ; ++s)
        buf[mi][s] = *(const short8*)(Ar + (size_t)mi * 16 * K + s * 32);
  };
  auto compCh = [&](short8 (&buf)[4][CSZ], int ch) {
#pragma unroll
    for (int s = 0; s < CSZ; ++s) {
      int it = ch * CSZ + s;
      short8 bfr[8];
#pragma unroll
      for (int ni = 0; ni < 8; ++ni)
        bfr[ni] = *(const short8*)(Blds + (ni * 16 + lr) * KP + it * 32 + lq * 8);
#pragma unroll
      for (int mi = 0; mi < 4; ++mi)
#pragma unroll
        for (int ni = 0; ni < 8; ++ni)
          acc[mi][ni] = __builtin_amdgcn_mfma_f32_16x16x32_bf16(buf[mi][s], bfr[ni], acc[mi][ni], 0, 0, 0);
    }
  };

  loadCh(bufE, t0, 0);

  for (int t = t0; t < t1; ++t) {
    int rowbase = t * 512 + wv * 64;
#pragma unroll
    for (int mi = 0; mi < 4; ++mi)
#pragma unroll
      for (int ni = 0; ni < 8; ++ni) acc[mi][ni] = (f32x4){0.f, 0.f, 0.f, 0.f};

#pragma unroll
    for (int ch = 0; ch < CH; ch += 2) {
      loadCh(bufO, t, ch + 1);               // issue odd chunk
      compCh(bufE, ch);                      // compute even (waits E only)
      if (ch + 2 < CH) loadCh(bufE, t, ch + 2);           // next even chunk
      else if (t + 1 < t1) loadCh(bufE, t + 1, 0);        // next tile, early
      compCh(bufO, ch + 1);                  // compute odd (waits O only)
    }

    // ---- epilogue (per-wave private strip, no barriers)
#pragma unroll
    for (int mi = 0; mi < 4; ++mi) {
#pragma unroll
      for (int ni = 0; ni < 8; ++ni) {
#pragma unroll
        for (int r = 0; r < 4; ++r) {
          float v = acc[mi][ni][r] + bvv[ni];
          if (relu) v = fmaxf(v, 0.f);
          strip[(lq * 4 + r) * CP + ni * 16 + lr] = f2b(v);
        }
      }
      int row16 = lane >> 2, cb = lane & 3;
      const u16* src = strip + row16 * CP + cb * 32;
      uint4 c0 = *(const uint4*)(src);
      uint4 c1 = *(const uint4*)(src + 8);
      uint4 c2 = *(const uint4*)(src + 16);
      uint4 c3 = *(const uint4*)(src + 24);
      int mrow = rowbase + mi * 16 + row16;
      u16* gout = Cb + (size_t)mrow * Nn + n0 + cb * 32;
      *(uint4*)(gout)      = c0;
      *(uint4*)(gout + 8)  = c1;
      *(uint4*)(gout + 16) = c2;
      *(uint4*)(gout + 24) = c3;

      if (aes) {
        const float* ap = asrc + n0 + cb * 32;
        const float* dp = adst + n0 + cb * 32;
        float se = 0.f, de = 0.f;
        uint4 cj[4] = {c0, c1, c2, c3};
#pragma unroll
        for (int j = 0; j < 4; ++j) {
          float4 A0 = *(const float4*)(ap + j * 8);
          float4 A1 = *(const float4*)(ap + j * 8 + 4);
          float4 D0 = *(const float4*)(dp + j * 8);
          float4 D1 = *(const float4*)(dp + j * 8 + 4);
          uint4 rv = cj[j];
          float v0 = bflo(rv.x), v1 = bfhi(rv.x), v2 = bflo(rv.y), v3 = bfhi(rv.y);
          float v4 = bflo(rv.z), v5 = bfhi(rv.z), v6 = bflo(rv.w), v7 = bfhi(rv.w);
          se += v0 * A0.x + v1 * A0.y + v2 * A0.z + v3 * A0.w
              + v4 * A1.x + v5 * A1.y + v6 * A1.z + v7 * A1.w;
          de += v0 * D0.x + v1 * D0.y + v2 * D0.z + v3 * D0.w
              + v4 * D1.x + v5 * D1.y + v6 * D1.z + v7 * D1.w;
        }
        se += __shfl_xor(se, 1); se += __shfl_xor(se, 2);
        de += __shfl_xor(de, 1); de += __shfl_xor(de, 2);
        if (cb == 0 && mrow < Mstore) {
          aes[mrow * 4 + nidx] = se;   // one writer per (row, head)
          aed[mrow * 4 + nidx] = de;
        }
      }
    }
  }
}

// ---------------------------------------------------------------- GAT aggregate
// Round-13 version: pure gather+FMA inner loop (p precomputed by mg_edge_p).
// Two-level software pipeline: IDX (colsrc+p, 2 groups ahead) / BLD (768 B
// B-row gather, 1 group ahead, 4 in flight) / CMP. Edge order of the fp32
// accumulation is unchanged (bit-identical to the sequential version).
__global__ __launch_bounds__(256) void mg_aggregate(
    const u16* __restrict__ B, const float* __restrict__ pcsr,
    const int* __restrict__ rowptr, const int* __restrict__ colsrc,
    const float* __restrict__ bias,
    u16* __restrict__ A, float* __restrict__ stats) {
  __shared__ float bS[4 * W3D];
  __shared__ float bQ[4 * W3D];
  int wv = threadIdx.x >> 6, lane = threadIdx.x & 63;
  if (lane < 48) {
    int h = lane >> 4;
    int cc = lane * 8;
    float4 bv0 = *(const float4*)(bias + cc);
    float4 bv1 = *(const float4*)(bias + cc + 4);
    float stS[8], stQ[8];
#pragma unroll
    for (int j = 0; j < 8; ++j) { stS[j] = 0.f; stQ[j] = 0.f; }
#pragma unroll
    for (int sub = 0; sub < 2; ++sub) {
      int n = blockIdx.x * 8 + wv * 2 + sub;       // 12500*8 == NN exactly
      int r0 = rowptr[n], r1 = rowptr[n + 1];      // r1 > r0 (self-loop)
      float accv[8];
#pragma unroll
      for (int j = 0; j < 8; ++j) accv[j] = 0.f;
      float ssum = 0.f;

      int   c0, c1, c2, c3, cb0, cb1, cb2, cb3;
      float p0, p1, p2, p3, pb0, pb1, pb2, pb3;
      uint4 v0, v1, v2, v3;

#define IDX_(CV, PV, RR) { int _i = ((RR) < r1) ? (RR) : (r1 - 1);          \
      CV = colsrc[_i]; PV = pcsr[(size_t)_i * 4 + h]; }
#define BLD_(VV, CV) { int _s = __builtin_amdgcn_readfirstlane(CV);         \
      VV = *(const uint4*)(B + (size_t)_s * W3D + cc); }
#define CMP_(PV, VV, RR) { float _pv = ((RR) < r1) ? PV : 0.f;              \
      ssum += _pv;                                                          \
      accv[0] += _pv * bflo(VV.x); accv[1] += _pv * bfhi(VV.x);             \
      accv[2] += _pv * bflo(VV.y); accv[3] += _pv * bfhi(VV.y);             \
      accv[4] += _pv * bflo(VV.z); accv[5] += _pv * bfhi(VV.z);             \
      accv[6] += _pv * bflo(VV.w); accv[7] += _pv * bfhi(VV.w); }

      IDX_(c0,  p0,  r0 + 0) IDX_(c1,  p1,  r0 + 1)
      IDX_(c2,  p2,  r0 + 2) IDX_(c3,  p3,  r0 + 3)
      IDX_(cb0, pb0, r0 + 4) IDX_(cb1, pb1, r0 + 5)
      IDX_(cb2, pb2, r0 + 6) IDX_(cb3, pb3, r0 + 7)
      BLD_(v0, c0) BLD_(v1, c1) BLD_(v2, c2) BLD_(v3, c3)

      for (int base = r0; base < r1; base += 4) {
        CMP_(p0, v0, base + 0)  BLD_(v0, cb0)
        CMP_(p1, v1, base + 1)  BLD_(v1, cb1)
        CMP_(p2, v2, base + 2)  BLD_(v2, cb2)
        CMP_(p3, v3, base + 3)  BLD_(v3, cb3)
        p0 = pb0; p1 = pb1; p2 = pb2; p3 = pb3;
        IDX_(cb0, pb0, base + 8)  IDX_(cb1, pb1, base + 9)
        IDX_(cb2, pb2, base + 10) IDX_(cb3, pb3, base + 11)
      }
#undef IDX_
#undef BLD_
#undef CMP_

      float inv = 1.0f / ssum;
      float v[8];
      v[0] = accv[0] * inv + bv0.x; v[1] = accv[1] * inv + bv0.y;
      v[2] = accv[2] * inv + bv0.z; v[3] = accv[3] * inv + bv0.w;
      v[4] = accv[4] * inv + bv1.x; v[5] = accv[5] * inv + bv1.y;
      v[6] = accv[6] * inv + bv1.z; v[7] = accv[7] * inv + bv1.w;
      uint4 st;
      st.x = (u32)f2b(v[0]) | ((u32)f2b(v[1]) << 16);
      st.y = (u32)f2b(v[2]) | ((u32)f2b(v[3]) << 16);
      st.z = (u32)f2b(v[4]) | ((u32)f2b(v[5]) << 16);
      st.w = (u32)f2b(v[6]) | ((u32)f2b(v[7]) << 16);
      *(uint4*)(A + (size_t)n * W3D + cc) = st;
#pragma unroll
      for (int j = 0; j < 8; ++j) { stS[j] += v[j]; stQ[j] += v[j] * v[j]; }
    }
    *(float4*)(bS + wv * W3D + cc)     = (float4){stS[0], stS[1], stS[2], stS[3]};
    *(float4*)(bS + wv * W3D + cc + 4) = (float4){stS[4], stS[5], stS[6], stS[7]};
    *(float4*)(bQ + wv * W3D + cc)     = (float4){stQ[0], stQ[1], stQ[2], stQ[3]};
    *(float4*)(bQ + wv * W3D + cc + 4) = (float4){stQ[4], stQ[5], stQ[6], stQ[7]};
  }
  __syncthreads();
  for (int t = threadIdx.x; t < W3D; t += 256) {
    float s = 0.f, q = 0.f;
#pragma unroll
    for (int w = 0; w < 4; ++w) { s += bS[w * W3D + t]; q += bQ[w * W3D + t]; }
    float* sl = stats + (size_t)(blockIdx.x & (NSLICE - 1)) * 768;
    atomicAdd(&sl[t], s);
    atomicAdd(&sl[W3D + t], q);
  }
}

// ---------------------------------------------------------------- BN finalize
__global__ void mg_bn_finalize(const float* __restrict__ stats, const float* __restrict__ gamma,
                               const float* __restrict__ beta, float* __restrict__ scale,
                               float* __restrict__ shift) {
  int c = threadIdx.x;   // 384 threads
  float s = 0.f, q = 0.f;
  for (int b = 0; b < NSLICE; ++b) { s += stats[b * 768 + c]; q += stats[b * 768 + W3D + c]; }
  const float invN = 1.0f / (float)NN;
  float mu = s * invN;
  float var = fmaxf(q * invN - mu * mu, 0.f);
  float inv = rsqrtf(var + 1e-5f);
  float g = gamma[c], be = beta[c];
  scale[c] = g * inv;
  shift[c] = be - mu * g * inv;
}

// ---------------------------------------------------------------- pool + head
__global__ void mg_pool(const u16* __restrict__ A, const float* __restrict__ scale,
                        const float* __restrict__ shift, const int* __restrict__ gptr,
                        float* __restrict__ pooled) {
  int g = blockIdx.x, c = threadIdx.x;   // 384 threads
  int r0 = gptr[g], r1 = gptr[g + 1];
  float acc = 0.f;
  for (int n = r0; n < r1; ++n) acc += bf2f(A[(size_t)n * W3D + c]);
  int cnt = r1 - r0;
  float v = (cnt > 0) ? (acc / (float)cnt) * scale[c] + shift[c] : 0.f;
  pooled[g * W3D + c] = v;
}

__global__ void mg_head(const float* __restrict__ pooled, const float* __restrict__ w3,
                        const float* __restrict__ b3, const float* __restrict__ w4,
                        const float* __restrict__ b4, float* __restrict__ out) {
  __shared__ float p[W3D];
  __shared__ float g2[HIDD];
  __shared__ float lg[NCLS];
  int g = blockIdx.x, t = threadIdx.x;   // 128 threads
  for (int i = t; i < W3D; i += 128) p[i] = pooled[g * W3D + i];
  __syncthreads();
  float acc = 0.f;
  for (int k = 0; k < W3D; ++k) acc += p[k] * w3[k * HIDD + t];
  g2[t] = fmaxf(acc + b3[t], 0.f);
  __syncthreads();
  if (t < NCLS) {
    float a = 0.f;
    for (int k = 0; k < HIDD; ++k) a += g2[k] * w4[k * NCLS + t];
    lg[t] = a + b4[t];
  }
  __syncthreads();
  if (t < NCLS) {
    float m = -1e30f;
#pragma unroll
    for (int j = 0; j < NCLS; ++j) m = fmaxf(m, lg[j]);
    float se = 0.f;
#pragma unroll
    for (int j = 0; j < NCLS; ++j) se += __expf(lg[j] - m);
    out[g * NCLS + t] = lg[t] - m - __logf(se);
  }
}

// ---------------------------------------------------------------- launch
extern "C" void kernel_launch(void* const* d_in, const int* in_sizes, int n_in,
                              void* d_out, int out_size, void* d_ws, size_t ws_size,
                              hipStream_t stream) {
  const float* x     = (const float*)d_in[0];
  const int*   ei    = (const int*)d_in[1];
  const int*   batch = (const int*)d_in[2];
  const float* w1    = (const float*)d_in[3];
  const float* b1    = (const float*)d_in[4];
  const float* w2    = (const float*)d_in[5];
  const float* b2    = (const float*)d_in[6];
  const float* w0    = (const float*)d_in[7];
  const float* as0   = (const float*)d_in[8];
  const float* ad0   = (const float*)d_in[9];
  const float* b0    = (const float*)d_in[10];
  const float* wl    = (const float*)d_in[11];
  const float* asl   = (const float*)d_in[12];
  const float* adl   = (const float*)d_in[13];
  const float* bl    = (const float*)d_in[14];
  const float* gamma = (const float*)d_in[15];
  const float* beta  = (const float*)d_in[16];
  const float* w3    = (const float*)d_in[17];
  const float* b3    = (const float*)d_in[18];
  const float* w4    = (const float*)d_in[19];
  const float* b4    = (const float*)d_in[20];
  float* out = (float*)d_out;

  char* w = (char*)d_ws;
  auto alloc = [&](size_t bytes) -> void* {
    void* p = (void*)w;
    w += (bytes + 255) & ~(size_t)255;
    return p;
  };
  u16*   P      = (u16*)alloc((size_t)NN2 * W3D * 2);  // gemm out / gather src
  u16*   Q      = (u16*)alloc((size_t)NN2 * W3D * 2);  // agg out / next gemm in
  float* es     = (float*)alloc((size_t)NN * 4 * 4);
  float* ed     = (float*)alloc((size_t)NN * 4 * 4);
  int*   deg    = (int*)alloc((size_t)NN * 4);
  int*   rowptr = (int*)alloc((size_t)(NN + 1) * 4);
  int*   fill   = (int*)alloc((size_t)NN * 4);
  int*   colsrc = (int*)alloc((size_t)ETOT * 4);
  int*   dstc   = (int*)alloc((size_t)ETOT * 4);
  float* pcsr   = (float*)alloc((size_t)ETOT * 4 * 4);
  int*   bsum   = (int*)alloc(256 * 4);
  float* stats  = (float*)alloc((size_t)NSLICE * 768 * 4);
  float* scale  = (float*)alloc(W3D * 4);
  float* shift  = (float*)alloc(W3D * 4);
  float* bprime = (float*)alloc(W3D * 4);
  int*   gptr   = (int*)alloc((size_t)(NG + 1) * 4);
  float* pooled = (float*)alloc((size_t)NG * W3D * 4);
  u16*   W1T    = (u16*)alloc((size_t)256 * 72 * 2);
  u16*   W2T    = (u16*)alloc((size_t)128 * 264 * 2);
  u16*   W0T    = (u16*)alloc((size_t)384 * 136 * 2);
  u16*   WlT    = (u16*)alloc((size_t)3 * 384 * 392 * 2);
  u16*   WpT    = (u16*)alloc((size_t)384 * 392 * 2);
  u16*   Xb     = Q;   // [NN2][64] bf16; Q is dead until stem2 writes it

  // Workspace too small -> clean zero output (diagnostic), no OOB
  if ((size_t)(w - (char*)d_ws) > ws_size) {
    mg_zero_out<<<(out_size + 255) / 256, 256, 0, stream>>>(out, out_size);
    return;
  }

  // input conversions (weights land transposed with 8-col zero pad)
  mg_cvt_x<<<(NN2 * 64 + 255) / 256, 256, 0, stream>>>(x, Xb);
  mg_transpose_pad<<<(256 * 72 + 255) / 256, 256, 0, stream>>>(w1, W1T, 32, 256, 72);
  mg_transpose_pad<<<(128 * 264 + 255) / 256, 256, 0, stream>>>(w2, W2T, 256, 128, 264);
  mg_transpose_pad<<<(384 * 136 + 255) / 256, 256, 0, stream>>>(w0, W0T, 128, 384, 136);
  for (int i = 0; i < 3; ++i)
    mg_transpose_pad<<<(384 * 392 + 255) / 256, 256, 0, stream>>>(
        wl + (size_t)i * 384 * 384, WlT + (size_t)i * 384 * 392, 384, 384, 392);

  // CSR by dst (built once, reused by all 4 layers)
  hipMemsetAsync(deg, 0, (size_t)NN * 4, stream);
  mg_edge_histo<<<(ETOT + 255) / 256, 256, 0, stream>>>(ei, deg);
  int nb = (NN + 1023) / 1024;   // 98
  mg_scan1<<<nb, 256, 0, stream>>>(deg, bsum, NN);
  mg_scan2<<<1, 256, 0, stream>>>(bsum, nb);
  mg_scan3<<<nb, 256, 0, stream>>>(deg, bsum, rowptr, NN);
  hipMemcpyAsync(fill, rowptr, (size_t)NN * 4, hipMemcpyDeviceToDevice, stream);
  mg_edge_scatter<<<(ETOT + 255) / 256, 256, 0, stream>>>(ei, fill, colsrc, dstc);
  mg_graph_ptr<<<(NG + 1 + 255) / 256, 256, 0, stream>>>(batch, gptr);

  dim3 blk(512);
  const int MT = NN2 / 512;   // 196 m-tiles of 512 rows
  const int EPB = (ETOT + 255) / 256;

  // stem: relu(x@W1+b1) -> relu(@W2+b2); P: [NN2][256], then Q: [NN2][128]
  mg_gemm<64><<<dim3(128, 2), blk, 0, stream>>>(Xb, W1T, MT, NN, 256,
                                                P, b1, 1,
                                                nullptr, nullptr, nullptr, nullptr);
  mg_gemm<256><<<dim3(196, 1), blk, 0, stream>>>(P, W2T, MT, NN, 128,
                                                 Q, b2, 1,
                                                 nullptr, nullptr, nullptr, nullptr);

  for (int i = 0; i < 4; ++i) {
    const float* bi_g = nullptr;   // GEMM bias (folded BN shift term)
    const u16* Bt;
    if (i == 0) {
      Bt = W0T;
    } else {
      // fold BN of previous layer into this layer's weights + bias
      mg_fold_w<<<384, 128, 0, stream>>>(WlT + (size_t)(i - 1) * 384 * 392,
                                         scale, shift, WpT, bprime);
      Bt = WpT;
      bi_g = bprime;
    }
    const float* as = (i == 0) ? as0 : (asl + (size_t)(i - 1) * 384);
    const float* ad = (i == 0) ? ad0 : (adl + (size_t)(i - 1) * 384);
    const float* bi = (i == 0) ? b0  : (bl  + (size_t)(i - 1) * 384);
    hipMemsetAsync(stats, 0, (size_t)NSLICE * 768 * 4, stream);
    if (i == 0)
      mg_gemm<128><<<dim3(85, 3), blk, 0, stream>>>(Q, Bt, MT, NN, W3D,
                                                    P, bi_g, 0,
                                                    as, ad, es, ed);
    else
      mg_gemm<384><<<dim3(85, 3), blk, 0, stream>>>(Q, Bt, MT, NN, W3D,
                                                    P, bi_g, 0,
                                                    as, ad, es, ed);
    mg_edge_p<<<EPB, 256, 0, stream>>>(colsrc, dstc, es, ed, pcsr);
    mg_aggregate<<<NN / 8, 256, 0, stream>>>(P, pcsr, rowptr, colsrc, bi, Q, stats);
    mg_bn_finalize<<<1, 384, 0, stream>>>(stats, gamma + (size_t)i * W3D,
                                          beta + (size_t)i * W3D, scale, shift);
  }

  // global mean pool (BN3 folded in) + MLP head + log_softmax
  mg_pool<<<NG, 384, 0, stream>>>(Q, scale, shift, gptr, pooled);
  mg_head<<<NG, 128, 0, stream>>>(pooled, w3, b3, w4, b4, out);
}

// Round 7
// 967.129 us; speedup vs baseline: 1.1251x; 1.1251x over previous
//
#include <hip/hip_runtime.h>

#define NN      100000      // nodes
#define NN2     100352      // nodes padded to 256 (392 tiles of 256)
#define NE      400000      // raw edges
#define ETOT    500000      // edges + self loops
#define NG      4000        // graphs
#define W3D     384
#define HIDD    128
#define NCLS    10
#define NSLICE  256         // stat accumulation slices

typedef unsigned short u16;
typedef unsigned int   u32;
typedef unsigned long long u64;
typedef __attribute__((ext_vector_type(8))) short short8;
typedef __attribute__((ext_vector_type(4))) float f32x4;

static __device__ __forceinline__ float bf2f(u16 u) {
  return __uint_as_float(((u32)u) << 16);
}
static __device__ __forceinline__ float bflo(u32 u) {
  return __uint_as_float(u << 16);
}
static __device__ __forceinline__ float bfhi(u32 u) {
  return __uint_as_float(u & 0xffff0000u);
}
static __device__ __forceinline__ u16 f2b(float f) {
  u32 u = __float_as_uint(f);
  u32 r = (u + 0x7fffu + ((u >> 16) & 1u)) >> 16;
  return (u16)r;
}

// async global->LDS, 16 B per lane; LDS dest = wave-uniform base + lane*16
static __device__ __forceinline__ void llds16(const u16* g, u16* l) {
  __builtin_amdgcn_global_load_lds(
      (const __attribute__((address_space(1))) void*)(u64)(const void*)g,
      (__attribute__((address_space(3))) void*)(u64)(void*)l, 16, 0, 0);
}

#define WAITV0() asm volatile("s_waitcnt vmcnt(0)" ::: "memory")

// ---------------------------------------------------------------- fallback
__global__ void mg_zero_out(float* out, int n) {
  int i = blockIdx.x * 256 + threadIdx.x;
  if (i < n) out[i] = 0.f;
}

// ---------------------------------------------------------------- x -> bf16 [NN2][64] zero-padded
__global__ void mg_cvt_x(const float* __restrict__ x, u16* __restrict__ Xb) {
  int idx = blockIdx.x * 256 + threadIdx.x;
  if (idx >= NN2 * 64) return;
  int row = idx >> 6, col = idx & 63;
  Xb[idx] = (row < NN && col < 32) ? f2b(x[row * 32 + col]) : (u16)0;
}

// ---------------------------------------------------------------- transpose
// out[n][kp] = bf16(in[kp][n]) for kp<K, zero-padded to Kpad (= K+8 pad for
// bank-conflict-reduced LDS rows; no swizzle).
__global__ void mg_transpose_pad(const float* __restrict__ in, u16* __restrict__ out,
                                 int K, int Nn, int Kpad) {
  int idx = blockIdx.x * 256 + threadIdx.x;
  if (idx >= Nn * Kpad) return;
  int n = idx / Kpad, kp = idx - n * Kpad;
  out[idx] = (kp < K) ? f2b(in[kp * Nn + n]) : (u16)0;
}

// ---------------------------------------------------------------- BN -> weight fold
// Wt [384][392] (8-col zero pad); output keeps the pad. Pads have w=0 so the
// clamped scale/shift index is harmless.
__global__ void mg_fold_w(const u16* __restrict__ Wt, const float* __restrict__ scale,
                          const float* __restrict__ shift, u16* __restrict__ Wp,
                          float* __restrict__ bp) {
  __shared__ float red[128];
  int j = blockIdx.x, t = threadIdx.x;   // 384 blocks x 128 threads
  const u16* src = Wt + (size_t)j * (W3D + 8);
  u16* dst = Wp + (size_t)j * (W3D + 8);
  float acc = 0.f;
  for (int kp = t; kp < W3D + 8; kp += 128) {
    int kt = (kp < W3D) ? kp : 0;
    float w = bf2f(src[kp]);             // pad entries are 0
    dst[kp] = f2b(w * scale[kt]);
    acc += w * shift[kt];
  }
  red[t] = acc; __syncthreads();
  for (int off = 64; off; off >>= 1) {
    if (t < off) red[t] += red[t + off];
    __syncthreads();
  }
  if (t == 0) bp[j] = red[0];
}

// ---------------------------------------------------------------- CSR build
__global__ void mg_edge_histo(const int* __restrict__ ei, int* __restrict__ deg) {
  int e = blockIdx.x * 256 + threadIdx.x;
  if (e >= ETOT) return;
  int d = (e < NE) ? ei[NE + e] : (e - NE);
  atomicAdd(&deg[d], 1);
}

__global__ void mg_scan1(const int* __restrict__ in, int* __restrict__ bsum, int n) {
  __shared__ int sd[256];
  int tid = threadIdx.x;
  int base = blockIdx.x * 1024 + tid * 4;
  int s = 0;
#pragma unroll
  for (int j = 0; j < 4; ++j) { int i = base + j; if (i < n) s += in[i]; }
  sd[tid] = s; __syncthreads();
  for (int off = 128; off > 0; off >>= 1) {
    if (tid < off) sd[tid] += sd[tid + off];
    __syncthreads();
  }
  if (tid == 0) bsum[blockIdx.x] = sd[0];
}

__global__ void mg_scan2(int* __restrict__ bsum, int nb) {
  __shared__ int sd[256];
  int tid = threadIdx.x;
  int v = (tid < nb) ? bsum[tid] : 0;
  sd[tid] = v; __syncthreads();
  for (int off = 1; off < 256; off <<= 1) {
    int t = (tid >= off) ? sd[tid - off] : 0;
    __syncthreads();
    sd[tid] += t;
    __syncthreads();
  }
  if (tid < nb) bsum[tid] = sd[tid] - v;   // exclusive
}

__global__ void mg_scan3(const int* __restrict__ in, const int* __restrict__ bexcl,
                         int* __restrict__ out, int n) {
  __shared__ int sd[256];
  int tid = threadIdx.x;
  int base = blockIdx.x * 1024 + tid * 4;
  int loc[4]; int s = 0;
#pragma unroll
  for (int j = 0; j < 4; ++j) { int i = base + j; loc[j] = (i < n) ? in[i] : 0; s += loc[j]; }
  sd[tid] = s; __syncthreads();
  for (int off = 1; off < 256; off <<= 1) {
    int t = (tid >= off) ? sd[tid - off] : 0;
    __syncthreads();
    sd[tid] += t;
    __syncthreads();
  }
  int run = sd[tid] - s + bexcl[blockIdx.x];
#pragma unroll
  for (int j = 0; j < 4; ++j) {
    int i = base + j;
    if (i < n) { out[i] = run; run += loc[j]; if (i == n - 1) out[n] = run; }
  }
}

__global__ void mg_edge_scatter(const int* __restrict__ ei, int* __restrict__ fill,
                                int* __restrict__ colsrc, int* __restrict__ dstc) {
  int e = blockIdx.x * 256 + threadIdx.x;
  if (e >= ETOT) return;
  int s, d;
  if (e < NE) { s = ei[e]; d = ei[NE + e]; } else { s = e - NE; d = s; }
  int pos = atomicAdd(&fill[d], 1);
  colsrc[pos] = s;
  dstc[pos] = d;
}

__global__ void mg_graph_ptr(const int* __restrict__ batch, int* __restrict__ gptr) {
  int g = blockIdx.x * 256 + threadIdx.x;
  if (g > NG) return;
  if (g == NG) { gptr[NG] = NN; return; }
  int lo = 0, hi = NN;
  while (lo < hi) { int mid = (lo + hi) >> 1; if (batch[mid] < g) lo = mid + 1; else hi = mid; }
  gptr[g] = lo;
}

// ---------------------------------------------------------------- edge softmax numerators
// es/ed arrive as PARTIAL dots: es8[n][8], slot nidx in 0..5, head h = slot/2;
// es[n][h] = es8[n][2h] + es8[n][2h+1] (the two 64-col GEMM blocks of head h).
__global__ __launch_bounds__(256) void mg_edge_p(
    const int* __restrict__ colsrc, const int* __restrict__ dstc,
    const float* __restrict__ es8, const float* __restrict__ ed8,
    float* __restrict__ pcsr) {
  int e = blockIdx.x * 256 + threadIdx.x;
  if (e >= ETOT) return;
  int s = colsrc[e], d = dstc[e];
  float4 sa0 = *(const float4*)(es8 + 8 * s);
  float4 sa1 = *(const float4*)(es8 + 8 * s + 4);
  float4 da0 = *(const float4*)(es8 + 8 * d);
  float4 da1 = *(const float4*)(es8 + 8 * d + 4);
  float4 dd0 = *(const float4*)(ed8 + 8 * d);
  float4 dd1 = *(const float4*)(ed8 + 8 * d + 4);
  float esx = sa0.x + sa0.y, esy = sa0.z + sa0.w, esz = sa1.x + sa1.y;
  float sdx = da0.x + da0.y, sdy = da0.z + da0.w, sdz = da1.x + da1.y;
  float ddx = dd0.x + dd0.y, ddy = dd0.z + dd0.w, ddz = dd1.x + dd1.y;
  float4 p;
  {
    float ev = esx + ddx; ev = (ev > 0.f) ? ev : 0.2f * ev;
    float mv = sdx + ddx; mv = (mv > 0.f) ? mv : 0.2f * mv;
    p.x = __expf(ev - mv);
  }
  {
    float ev = esy + ddy; ev = (ev > 0.f) ? ev : 0.2f * ev;
    float mv = sdy + ddy; mv = (mv > 0.f) ? mv : 0.2f * mv;
    p.y = __expf(ev - mv);
  }
  {
    float ev = esz + ddz; ev = (ev > 0.f) ? ev : 0.2f * ev;
    float mv = sdz + ddz; mv = (mv > 0.f) ? mv : 0.2f * mv;
    p.z = __expf(ev - mv);
  }
  p.w = 0.f;
  *(float4*)(pcsr + (size_t)e * 4) = p;
}

// ---------------------------------------------------------------- GEMM (bf16 MFMA)
// Round-16: occupancy fix. Round-5's best structure (86us: chunked A pipeline,
// padded B, barrier-free) but GBN=64 -> B LDS <= 50KB, strip 72 -> LDS 68.6KB
// -> 2 blocks/CU = 4 waves/SIMD (was 2). Diagnosis: 5 structural variants all
// stuck at 86-115us, MfmaUtil 10-13%, Occupancy 15-19% -> the invariant was
// 1 block/CU; latency serialization needs resident waves, not schedule depth.
// aes/aed become per-block PARTIAL dots in [NN][8] (slot = nidx), summed by
// mg_edge_p -- no atomics, deterministic.
#define CPN 72   // C-strip LDS row stride (u16), 16B-aligned rows

template<int K>
__global__ __launch_bounds__(512, 4) void mg_gemm(
    const u16* __restrict__ Ag, const u16* __restrict__ Bt,
    int MT, int Mstore, int Nn,
    u16* __restrict__ Cb, const float* __restrict__ bias, int relu,
    const float* __restrict__ asrc, const float* __restrict__ adst,
    float* __restrict__ aes, float* __restrict__ aed) {
  constexpr int KP = K + 8;
  constexpr int NITER = K / 32;
  constexpr int CSZ = (K == 64) ? 1 : 2;
  constexpr int CH = NITER / CSZ;        // 2,2,4,6 -> always even
  static_assert(CH * CSZ == NITER && (CH & 1) == 0, "chunking");
  __shared__ u16 lds[64 * KP + 8 * 16 * CPN];
  u16* Blds = lds;
  int tid = threadIdx.x;
  int lane = tid & 63, wv = tid >> 6;

  // bijective XCD swizzle: work chunks per XCD contiguous, n-tile fastest
  int gx = gridDim.x, gy = gridDim.y;
  int nwg = gx * gy;
  int lin = (int)blockIdx.y * gx + blockIdx.x;
  int q = nwg >> 3, r8 = nwg & 7;
  int xcd = lin & 7, sidx = lin >> 3;
  int nlin = (xcd < r8) ? (xcd * (q + 1) + sidx)
                        : (r8 * (q + 1) + (xcd - r8) * q + sidx);
  int mchunk = nlin / gy;
  int nidx = nlin - mchunk * gy;
  int n0 = nidx * 64;

  int lr = lane & 15, lq = lane >> 4;

  // ---- stage the full B n-tile: 64*KP*2 bytes, linear copy
  {
    const u16* Bg = Bt + (size_t)n0 * KP;
    constexpr int BBYTES = 64 * KP * 2;
    constexpr int FULL = BBYTES / 8192;            // full 512-thread rounds
    constexpr int REMC = (BBYTES - FULL * 8192) / 16;  // leftover 16B chunks
#pragma unroll
    for (int s = 0; s < FULL; ++s) {
      int off = s * 4096 + wv * 512 + lane * 8;    // u16 units
      llds16(Bg + off, Blds + off);
    }
    if (REMC > 0 && wv * 64 + lane < REMC) {
      int off = FULL * 4096 + wv * 512 + lane * 8;
      llds16(Bg + off, Blds + off);
    }
  }

  // per-lane GEMM bias (col = n0 + ni*16 + lr)
  float bvv[4];
#pragma unroll
  for (int ni = 0; ni < 4; ++ni)
    bvv[ni] = bias ? bias[n0 + ni * 16 + lr] : 0.f;

  WAITV0();
  __syncthreads();   // the ONLY barrier: B tile visible to all waves

  u16* strip = lds + 64 * KP + wv * (16 * CPN);

  int t0 = (int)(((long long)mchunk * MT) / gx);
  int t1 = (int)(((long long)(mchunk + 1) * MT) / gx);

  f32x4 acc[2][4];
  short8 bufE[2][CSZ], bufO[2][CSZ];

  auto loadCh = [&](short8 (&buf)[2][CSZ], int t, int ch) {
    const u16* Ar = Ag + (size_t)(t * 256 + wv * 32 + lr) * K + lq * 8 + ch * (CSZ * 32);
#pragma unroll
    for (int mi = 0; mi < 2; ++mi)
#pragma unroll
      for (int s = 0; s < CSZ; ++s)
        buf[mi][s] = *(const short8*)(Ar + (size_t)mi * 16 * K + s * 32);
  };
  auto compCh = [&](short8 (&buf)[2][CSZ], int ch) {
#pragma unroll
    for (int s = 0; s < CSZ; ++s) {
      int it = ch * CSZ + s;
      short8 bfr[4];
#pragma unroll
      for (int ni = 0; ni < 4; ++ni)
        bfr[ni] = *(const short8*)(Blds + (ni * 16 + lr) * KP + it * 32 + lq * 8);
#pragma unroll
      for (int mi = 0; mi < 2; ++mi)
#pragma unroll
        for (int ni = 0; ni < 4; ++ni)
          acc[mi][ni] = __builtin_amdgcn_mfma_f32_16x16x32_bf16(buf[mi][s], bfr[ni], acc[mi][ni], 0, 0, 0);
    }
  };

  loadCh(bufE, t0, 0);

  for (int t = t0; t < t1; ++t) {
    int rowbase = t * 256 + wv * 32;
#pragma unroll
    for (int mi = 0; mi < 2; ++mi)
#pragma unroll
      for (int ni = 0; ni < 4; ++ni) acc[mi][ni] = (f32x4){0.f, 0.f, 0.f, 0.f};

#pragma unroll
    for (int ch = 0; ch < CH; ch += 2) {
      loadCh(bufO, t, ch + 1);               // issue odd chunk
      compCh(bufE, ch);                      // compute even (waits E only)
      if (ch + 2 < CH) loadCh(bufE, t, ch + 2);           // next even chunk
      else if (t + 1 < t1) loadCh(bufE, t + 1, 0);        // next tile, early
      compCh(bufO, ch + 1);                  // compute odd (waits O only)
    }

    // ---- epilogue (per-wave private 16x64 strip, no barriers)
#pragma unroll
    for (int mi = 0; mi < 2; ++mi) {
#pragma unroll
      for (int ni = 0; ni < 4; ++ni) {
#pragma unroll
        for (int r = 0; r < 4; ++r) {
          float v = acc[mi][ni][r] + bvv[ni];
          if (relu) v = fmaxf(v, 0.f);
          strip[(lq * 4 + r) * CPN + ni * 16 + lr] = f2b(v);
        }
      }
      int row16 = lane >> 2, cb = lane & 3;   // 16 rows x 4 col-chunks of 16
      const u16* src = strip + row16 * CPN + cb * 16;
      uint4 c0 = *(const uint4*)(src);
      uint4 c1 = *(const uint4*)(src + 8);
      int mrow = rowbase + mi * 16 + row16;
      u16* gout = Cb + (size_t)mrow * Nn + n0 + cb * 16;
      *(uint4*)(gout)     = c0;
      *(uint4*)(gout + 8) = c1;

      if (aes) {
        const float* ap = asrc + n0 + cb * 16;
        const float* dp = adst + n0 + cb * 16;
        float4 A0 = *(const float4*)(ap);
        float4 A1 = *(const float4*)(ap + 4);
        float4 A2 = *(const float4*)(ap + 8);
        float4 A3 = *(const float4*)(ap + 12);
        float4 D0 = *(const float4*)(dp);
        float4 D1 = *(const float4*)(dp + 4);
        float4 D2 = *(const float4*)(dp + 8);
        float4 D3 = *(const float4*)(dp + 12);
        float se, de;
        {
          float v0 = bflo(c0.x), v1 = bfhi(c0.x), v2 = bflo(c0.y), v3 = bfhi(c0.y);
          float v4 = bflo(c0.z), v5 = bfhi(c0.z), v6 = bflo(c0.w), v7 = bfhi(c0.w);
          se = v0 * A0.x + v1 * A0.y + v2 * A0.z + v3 * A0.w
             + v4 * A1.x + v5 * A1.y + v6 * A1.z + v7 * A1.w;
          de = v0 * D0.x + v1 * D0.y + v2 * D0.z + v3 * D0.w
             + v4 * D1.x + v5 * D1.y + v6 * D1.z + v7 * D1.w;
        }
        {
          float v0 = bflo(c1.x), v1 = bfhi(c1.x), v2 = bflo(c1.y), v3 = bfhi(c1.y);
          float v4 = bflo(c1.z), v5 = bfhi(c1.z), v6 = bflo(c1.w), v7 = bfhi(c1.w);
          se += v0 * A2.x + v1 * A2.y + v2 * A2.z + v3 * A2.w
              + v4 * A3.x + v5 * A3.y + v6 * A3.z + v7 * A3.w;
          de += v0 * D2.x + v1 * D2.y + v2 * D2.z + v3 * D2.w
              + v4 * D3.x + v5 * D3.y + v6 * D3.z + v7 * D3.w;
        }
        se += __shfl_xor(se, 1); se += __shfl_xor(se, 2);
        de += __shfl_xor(de, 1); de += __shfl_xor(de, 2);
        if (cb == 0 && mrow < Mstore) {
          aes[(size_t)mrow * 8 + nidx] = se;   // PARTIAL dot (64 cols), slot=nidx
          aed[(size_t)mrow * 8 + nidx] = de;
        }
      }
    }
  }
}

// ---------------------------------------------------------------- GAT aggregate
// Round-13 version: pure gather+FMA inner loop (p precomputed by mg_edge_p).
// Two-level software pipeline: IDX (colsrc+p, 2 groups ahead) / BLD (768 B
// B-row gather, 1 group ahead, 4 in flight) / CMP. Edge order of the fp32
// accumulation is unchanged (bit-identical to the sequential version).
__global__ __launch_bounds__(256) void mg_aggregate(
    const u16* __restrict__ B, const float* __restrict__ pcsr,
    const int* __restrict__ rowptr, const int* __restrict__ colsrc,
    const float* __restrict__ bias,
    u16* __restrict__ A, float* __restrict__ stats) {
  __shared__ float bS[4 * W3D];
  __shared__ float bQ[4 * W3D];
  int wv = threadIdx.x >> 6, lane = threadIdx.x & 63;
  if (lane < 48) {
    int h = lane >> 4;
    int cc = lane * 8;
    float4 bv0 = *(const float4*)(bias + cc);
    float4 bv1 = *(const float4*)(bias + cc + 4);
    float stS[8], stQ[8];
#pragma unroll
    for (int j = 0; j < 8; ++j) { stS[j] = 0.f; stQ[j] = 0.f; }
#pragma unroll
    for (int sub = 0; sub < 2; ++sub) {
      int n = blockIdx.x * 8 + wv * 2 + sub;       // 12500*8 == NN exactly
      int r0 = rowptr[n], r1 = rowptr[n + 1];      // r1 > r0 (self-loop)
      float accv[8];
#pragma unroll
      for (int j = 0; j < 8; ++j) accv[j] = 0.f;
      float ssum = 0.f;

      int   c0, c1, c2, c3, cb0, cb1, cb2, cb3;
      float p0, p1, p2, p3, pb0, pb1, pb2, pb3;
      uint4 v0, v1, v2, v3;

#define IDX_(CV, PV, RR) { int _i = ((RR) < r1) ? (RR) : (r1 - 1);          \
      CV = colsrc[_i]; PV = pcsr[(size_t)_i * 4 + h]; }
#define BLD_(VV, CV) { int _s = __builtin_amdgcn_readfirstlane(CV);         \
      VV = *(const uint4*)(B + (size_t)_s * W3D + cc); }
#define CMP_(PV, VV, RR) { float _pv = ((RR) < r1) ? PV : 0.f;              \
      ssum += _pv;                                                          \
      accv[0] += _pv * bflo(VV.x); accv[1] += _pv * bfhi(VV.x);             \
      accv[2] += _pv * bflo(VV.y); accv[3] += _pv * bfhi(VV.y);             \
      accv[4] += _pv * bflo(VV.z); accv[5] += _pv * bfhi(VV.z);             \
      accv[6] += _pv * bflo(VV.w); accv[7] += _pv * bfhi(VV.w); }

      IDX_(c0,  p0,  r0 + 0) IDX_(c1,  p1,  r0 + 1)
      IDX_(c2,  p2,  r0 + 2) IDX_(c3,  p3,  r0 + 3)
      IDX_(cb0, pb0, r0 + 4) IDX_(cb1, pb1, r0 + 5)
      IDX_(cb2, pb2, r0 + 6) IDX_(cb3, pb3, r0 + 7)
      BLD_(v0, c0) BLD_(v1, c1) BLD_(v2, c2) BLD_(v3, c3)

      for (int base = r0; base < r1; base += 4) {
        CMP_(p0, v0, base + 0)  BLD_(v0, cb0)
        CMP_(p1, v1, base + 1)  BLD_(v1, cb1)
        CMP_(p2, v2, base + 2)  BLD_(v2, cb2)
        CMP_(p3, v3, base + 3)  BLD_(v3, cb3)
        p0 = pb0; p1 = pb1; p2 = pb2; p3 = pb3;
        IDX_(cb0, pb0, base + 8)  IDX_(cb1, pb1, base + 9)
        IDX_(cb2, pb2, base + 10) IDX_(cb3, pb3, base + 11)
      }
#undef IDX_
#undef BLD_
#undef CMP_

      float inv = 1.0f / ssum;
      float v[8];
      v[0] = accv[0] * inv + bv0.x; v[1] = accv[1] * inv + bv0.y;
      v[2] = accv[2] * inv + bv0.z; v[3] = accv[3] * inv + bv0.w;
      v[4] = accv[4] * inv + bv1.x; v[5] = accv[5] * inv + bv1.y;
      v[6] = accv[6] * inv + bv1.z; v[7] = accv[7] * inv + bv1.w;
      uint4 st;
      st.x = (u32)f2b(v[0]) | ((u32)f2b(v[1]) << 16);
      st.y = (u32)f2b(v[2]) | ((u32)f2b(v[3]) << 16);
      st.z = (u32)f2b(v[4]) | ((u32)f2b(v[5]) << 16);
      st.w = (u32)f2b(v[6]) | ((u32)f2b(v[7]) << 16);
      *(uint4*)(A + (size_t)n * W3D + cc) = st;
#pragma unroll
      for (int j = 0; j < 8; ++j) { stS[j] += v[j]; stQ[j] += v[j] * v[j]; }
    }
    *(float4*)(bS + wv * W3D + cc)     = (float4){stS[0], stS[1], stS[2], stS[3]};
    *(float4*)(bS + wv * W3D + cc + 4) = (float4){stS[4], stS[5], stS[6], stS[7]};
    *(float4*)(bQ + wv * W3D + cc)     = (float4){stQ[0], stQ[1], stQ[2], stQ[3]};
    *(float4*)(bQ + wv * W3D + cc + 4) = (float4){stQ[4], stQ[5], stQ[6], stQ[7]};
  }
  __syncthreads();
  for (int t = threadIdx.x; t < W3D; t += 256) {
    float s = 0.f, q = 0.f;
#pragma unroll
    for (int w = 0; w < 4; ++w) { s += bS[w * W3D + t]; q += bQ[w * W3D + t]; }
    float* sl = stats + (size_t)(blockIdx.x & (NSLICE - 1)) * 768;
    atomicAdd(&sl[t], s);
    atomicAdd(&sl[W3D + t], q);
  }
}

// ---------------------------------------------------------------- BN finalize
__global__ void mg_bn_finalize(const float* __restrict__ stats, const float* __restrict__ gamma,
                               const float* __restrict__ beta, float* __restrict__ scale,
                               float* __restrict__ shift) {
  int c = threadIdx.x;   // 384 threads
  float s = 0.f, q = 0.f;
  for (int b = 0; b < NSLICE; ++b) { s += stats[b * 768 + c]; q += stats[b * 768 + W3D + c]; }
  const float invN = 1.0f / (float)NN;
  float mu = s * invN;
  float var = fmaxf(q * invN - mu * mu, 0.f);
  float inv = rsqrtf(var + 1e-5f);
  float g = gamma[c], be = beta[c];
  scale[c] = g * inv;
  shift[c] = be - mu * g * inv;
}

// ---------------------------------------------------------------- pool + head
__global__ void mg_pool(const u16* __restrict__ A, const float* __restrict__ scale,
                        const float* __restrict__ shift, const int* __restrict__ gptr,
                        float* __restrict__ pooled) {
  int g = blockIdx.x, c = threadIdx.x;   // 384 threads
  int r0 = gptr[g], r1 = gptr[g + 1];
  float acc = 0.f;
  for (int n = r0; n < r1; ++n) acc += bf2f(A[(size_t)n * W3D + c]);
  int cnt = r1 - r0;
  float v = (cnt > 0) ? (acc / (float)cnt) * scale[c] + shift[c] : 0.f;
  pooled[g * W3D + c] = v;
}

__global__ void mg_head(const float* __restrict__ pooled, const float* __restrict__ w3,
                        const float* __restrict__ b3, const float* __restrict__ w4,
                        const float* __restrict__ b4, float* __restrict__ out) {
  __shared__ float p[W3D];
  __shared__ float g2[HIDD];
  __shared__ float lg[NCLS];
  int g = blockIdx.x, t = threadIdx.x;   // 128 threads
  for (int i = t; i < W3D; i += 128) p[i] = pooled[g * W3D + i];
  __syncthreads();
  float acc = 0.f;
  for (int k = 0; k < W3D; ++k) acc += p[k] * w3[k * HIDD + t];
  g2[t] = fmaxf(acc + b3[t], 0.f);
  __syncthreads();
  if (t < NCLS) {
    float a = 0.f;
    for (int k = 0; k < HIDD; ++k) a += g2[k] * w4[k * NCLS + t];
    lg[t] = a + b4[t];
  }
  __syncthreads();
  if (t < NCLS) {
    float m = -1e30f;
#pragma unroll
    for (int j = 0; j < NCLS; ++j) m = fmaxf(m, lg[j]);
    float se = 0.f;
#pragma unroll
    for (int j = 0; j < NCLS; ++j) se += __expf(lg[j] - m);
    out[g * NCLS + t] = lg[t] - m - __logf(se);
  }
}

// ---------------------------------------------------------------- launch
extern "C" void kernel_launch(void* const* d_in, const int* in_sizes, int n_in,
                              void* d_out, int out_size, void* d_ws, size_t ws_size,
                              hipStream_t stream) {
  const float* x     = (const float*)d_in[0];
  const int*   ei    = (const int*)d_in[1];
  const int*   batch = (const int*)d_in[2];
  const float* w1    = (const float*)d_in[3];
  const float* b1    = (const float*)d_in[4];
  const float* w2    = (const float*)d_in[5];
  const float* b2    = (const float*)d_in[6];
  const float* w0    = (const float*)d_in[7];
  const float* as0   = (const float*)d_in[8];
  const float* ad0   = (const float*)d_in[9];
  const float* b0    = (const float*)d_in[10];
  const float* wl    = (const float*)d_in[11];
  const float* asl   = (const float*)d_in[12];
  const float* adl   = (const float*)d_in[13];
  const float* bl    = (const float*)d_in[14];
  const float* gamma = (const float*)d_in[15];
  const float* beta  = (const float*)d_in[16];
  const float* w3    = (const float*)d_in[17];
  const float* b3    = (const float*)d_in[18];
  const float* w4    = (const float*)d_in[19];
  const float* b4    = (const float*)d_in[20];
  float* out = (float*)d_out;

  char* w = (char*)d_ws;
  auto alloc = [&](size_t bytes) -> void* {
    void* p = (void*)w;
    w += (bytes + 255) & ~(size_t)255;
    return p;
  };
  u16*   P      = (u16*)alloc((size_t)NN2 * W3D * 2);  // gemm out / gather src
  u16*   Q      = (u16*)alloc((size_t)NN2 * W3D * 2);  // agg out / next gemm in
  float* es     = (float*)alloc((size_t)NN * 8 * 4);   // partial dots [NN][8]
  float* ed     = (float*)alloc((size_t)NN * 8 * 4);
  int*   deg    = (int*)alloc((size_t)NN * 4);
  int*   rowptr = (int*)alloc((size_t)(NN + 1) * 4);
  int*   fill   = (int*)alloc((size_t)NN * 4);
  int*   colsrc = (int*)alloc((size_t)ETOT * 4);
  int*   dstc   = (int*)alloc((size_t)ETOT * 4);
  float* pcsr   = (float*)alloc((size_t)ETOT * 4 * 4);
  int*   bsum   = (int*)alloc(256 * 4);
  float* stats  = (float*)alloc((size_t)NSLICE * 768 * 4);
  float* scale  = (float*)alloc(W3D * 4);
  float* shift  = (float*)alloc(W3D * 4);
  float* bprime = (float*)alloc(W3D * 4);
  int*   gptr   = (int*)alloc((size_t)(NG + 1) * 4);
  float* pooled = (float*)alloc((size_t)NG * W3D * 4);
  u16*   W1T    = (u16*)alloc((size_t)256 * 72 * 2);
  u16*   W2T    = (u16*)alloc((size_t)128 * 264 * 2);
  u16*   W0T    = (u16*)alloc((size_t)384 * 136 * 2);
  u16*   WlT    = (u16*)alloc((size_t)3 * 384 * 392 * 2);
  u16*   WpT    = (u16*)alloc((size_t)384 * 392 * 2);
  u16*   Xb     = Q;   // [NN2][64] bf16; Q is dead until stem2 writes it

  // Workspace too small -> clean zero output (diagnostic), no OOB
  if ((size_t)(w - (char*)d_ws) > ws_size) {
    mg_zero_out<<<(out_size + 255) / 256, 256, 0, stream>>>(out, out_size);
    return;
  }

  // input conversions (weights land transposed with 8-col zero pad)
  mg_cvt_x<<<(NN2 * 64 + 255) / 256, 256, 0, stream>>>(x, Xb);
  mg_transpose_pad<<<(256 * 72 + 255) / 256, 256, 0, stream>>>(w1, W1T, 32, 256, 72);
  mg_transpose_pad<<<(128 * 264 + 255) / 256, 256, 0, stream>>>(w2, W2T, 256, 128, 264);
  mg_transpose_pad<<<(384 * 136 + 255) / 256, 256, 0, stream>>>(w0, W0T, 128, 384, 136);
  for (int i = 0; i < 3; ++i)
    mg_transpose_pad<<<(384 * 392 + 255) / 256, 256, 0, stream>>>(
        wl + (size_t)i * 384 * 384, WlT + (size_t)i * 384 * 392, 384, 384, 392);

  // CSR by dst (built once, reused by all 4 layers)
  hipMemsetAsync(deg, 0, (size_t)NN * 4, stream);
  mg_edge_histo<<<(ETOT + 255) / 256, 256, 0, stream>>>(ei, deg);
  int nb = (NN + 1023) / 1024;   // 98
  mg_scan1<<<nb, 256, 0, stream>>>(deg, bsum, NN);
  mg_scan2<<<1, 256, 0, stream>>>(bsum, nb);
  mg_scan3<<<nb, 256, 0, stream>>>(deg, bsum, rowptr, NN);
  hipMemcpyAsync(fill, rowptr, (size_t)NN * 4, hipMemcpyDeviceToDevice, stream);
  mg_edge_scatter<<<(ETOT + 255) / 256, 256, 0, stream>>>(ei, fill, colsrc, dstc);
  mg_graph_ptr<<<(NG + 1 + 255) / 256, 256, 0, stream>>>(batch, gptr);

  dim3 blk(512);
  const int MT = NN2 / 256;   // 392 m-tiles of 256 rows
  const int EPB = (ETOT + 255) / 256;

  // stem: relu(x@W1+b1) -> relu(@W2+b2); P: [NN2][256], then Q: [NN2][128]
  mg_gemm<64><<<dim3(128, 4), blk, 0, stream>>>(Xb, W1T, MT, NN, 256,
                                                P, b1, 1,
                                                nullptr, nullptr, nullptr, nullptr);
  mg_gemm<256><<<dim3(256, 2), blk, 0, stream>>>(P, W2T, MT, NN, 128,
                                                 Q, b2, 1,
                                                 nullptr, nullptr, nullptr, nullptr);

  for (int i = 0; i < 4; ++i) {
    const float* bi_g = nullptr;   // GEMM bias (folded BN shift term)
    const u16* Bt;
    if (i == 0) {
      Bt = W0T;
    } else {
      // fold BN of previous layer into this layer's weights + bias
      mg_fold_w<<<384, 128, 0, stream>>>(WlT + (size_t)(i - 1) * 384 * 392,
                                         scale, shift, WpT, bprime);
      Bt = WpT;
      bi_g = bprime;
    }
    const float* as = (i == 0) ? as0 : (asl + (size_t)(i - 1) * 384);
    const float* ad = (i == 0) ? ad0 : (adl + (size_t)(i - 1) * 384);
    const float* bi = (i == 0) ? b0  : (bl  + (size_t)(i - 1) * 384);
    hipMemsetAsync(stats, 0, (size_t)NSLICE * 768 * 4, stream);
    if (i == 0)
      mg_gemm<128><<<dim3(85, 6), blk, 0, stream>>>(Q, Bt, MT, NN, W3D,
                                                    P, bi_g, 0,
                                                    as, ad, es, ed);
    else
      mg_gemm<384><<<dim3(85, 6), blk, 0, stream>>>(Q, Bt, MT, NN, W3D,
                                                    P, bi_g, 0,
                                                    as, ad, es, ed);
    mg_edge_p<<<EPB, 256, 0, stream>>>(colsrc, dstc, es, ed, pcsr);
    mg_aggregate<<<NN / 8, 256, 0, stream>>>(P, pcsr, rowptr, colsrc, bi, Q, stats);
    mg_bn_finalize<<<1, 384, 0, stream>>>(stats, gamma + (size_t)i * W3D,
                                          beta + (size_t)i * W3D, scale, shift);
  }

  // global mean pool (BN3 folded in) + MLP head + log_softmax
  mg_pool<<<NG, 384, 0, stream>>>(Q, scale, shift, gptr, pooled);
  mg_head<<<NG, 128, 0, stream>>>(pooled, w3, b3, w4, b4, out);
}